// Round 1
// baseline (105.368 us; speedup 1.0000x reference)
//
#include <hip/hip_runtime.h>

// PlanarFlow: x = z + tanh(z@W0 + b0) @ W1 ; log_det = log|1 + (1-t^2)*(W0.W1)|
// z: [N,64] f32, W0: [64,1], b0: [1], W1: [1,64]
// d_out: x (N*64 floats) followed by log_det (N floats).
//
// Memory-bound: ~516 MB traffic. 16 lanes per row, float4 per lane,
// shfl_xor reduction within 16-lane groups for the row dot product.

__global__ __launch_bounds__(256) void planar_flow_kernel(
    const float* __restrict__ z,
    const float* __restrict__ W0,
    const float* __restrict__ b0,
    const float* __restrict__ W1,
    float* __restrict__ x,
    float* __restrict__ log_det,
    int n_rows)
{
    const int tid    = blockIdx.x * blockDim.x + threadIdx.x;
    const int l      = threadIdx.x & 15;                    // lane within 16-group (column quad)
    const int g0     = tid >> 4;                            // starting row
    const int stride = (gridDim.x * blockDim.x) >> 4;       // rows per grid step

    // Per-thread W fragments (columns 4l..4l+3), loaded once (L2/L1-resident).
    const float4 w0 = reinterpret_cast<const float4*>(W0)[l];
    const float4 w1 = reinterpret_cast<const float4*>(W1)[l];
    const float bias = b0[0];

    // s = W0 . W1 (scalar), reduced across the 16-lane group.
    float s = w0.x * w1.x + w0.y * w1.y + w0.z * w1.z + w0.w * w1.w;
    s += __shfl_xor(s, 1);
    s += __shfl_xor(s, 2);
    s += __shfl_xor(s, 4);
    s += __shfl_xor(s, 8);

    for (int row = g0; row < n_rows; row += stride) {
        const int idx = row * 16 + l;  // float4 index
        const float4 zv = reinterpret_cast<const float4*>(z)[idx];

        // a = z[row,:] . W0  (partial per lane, then 16-lane reduce)
        float a = zv.x * w0.x + zv.y * w0.y + zv.z * w0.z + zv.w * w0.w;
        a += __shfl_xor(a, 1);
        a += __shfl_xor(a, 2);
        a += __shfl_xor(a, 4);
        a += __shfl_xor(a, 8);
        a += bias;

        // tanh(a) = 1 - 2/(exp(2a)+1); saturates to +/-1 correctly.
        const float e = __expf(2.0f * a);
        const float t = 1.0f - 2.0f / (e + 1.0f);

        float4 xv;
        xv.x = fmaf(t, w1.x, zv.x);
        xv.y = fmaf(t, w1.y, zv.y);
        xv.z = fmaf(t, w1.z, zv.z);
        xv.w = fmaf(t, w1.w, zv.w);
        reinterpret_cast<float4*>(x)[idx] = xv;

        if (l == 0) {
            const float det = fmaf(1.0f - t * t, s, 1.0f);
            log_det[row] = __logf(fabsf(det));
        }
    }
}

extern "C" void kernel_launch(void* const* d_in, const int* in_sizes, int n_in,
                              void* d_out, int out_size, void* d_ws, size_t ws_size,
                              hipStream_t stream) {
    const float* z  = (const float*)d_in[0];
    const float* W0 = (const float*)d_in[1];
    const float* b0 = (const float*)d_in[2];
    const float* W1 = (const float*)d_in[3];

    const int n_rows = in_sizes[0] / 64;          // 1048576
    float* x       = (float*)d_out;               // [N,64]
    float* log_det = x + (size_t)n_rows * 64;     // [N]

    const int block = 256;
    const int grid  = 4096;                       // grid-stride over rows
    planar_flow_kernel<<<grid, block, 0, stream>>>(z, W0, b0, W1, x, log_det, n_rows);
}